// Round 9
// baseline (256.279 us; speedup 1.0000x reference)
//
#include <hip/hip_runtime.h>
#include <cstddef>
#include <cstdint>

#define Bn 128
#define Pn 8732
#define Cn 21
#define On 16
#define H0CNT 4352            // half 0: priors [0,4352), 68 chunks of 64
#define H1CNT 4380            // half 1: priors [4352,8732), 68 full + 1x28
#define MAGIC 0x13579BDFu

__device__ __forceinline__ void argmax_combine(float& v, int& p, float v2, int p2) {
  if (v2 > v || (v2 == v && p2 < p)) { v = v2; p = p2; }
}

// async 16B global -> LDS (wave-uniform LDS base; HW scatters lane*16)
__device__ __forceinline__ void cp16_lds(const float4* g, float4* l) {
  __builtin_amdgcn_global_load_lds(
      (const __attribute__((address_space(1))) unsigned int*)g,
      (__attribute__((address_space(3))) unsigned int*)l, 16, 0, 0);
}

// ---------------------------------------------------------------------------
// 256 blocks x 512 thr (2 blocks/CU via ~67KB LDS): block pair (2b,2b+1)
// handles image b, half h = blockIdx.x & 1.
// A: IoU matching own half -> s_bti; per-truth argmax -> u64 atomicMax keys.
// B: stream own-half conf via global_load_lds (chunks ci=wv+8i), softmax->s_ce.
// C: keys sync -> forced matches -> ce_neg regs, np/loc/cep partials;
//    np exchanged via tagged atomics (poison-safe).
// D: 4-pass radix select in PAIR LOCKSTEP: per-pass 256-bin histogram
//    exchange (additive), both halves pick the same bin deterministically.
// E: half1 posts partials; half0 combines -> res[b]; block 0 reduces 128.
// ---------------------------------------------------------------------------
__global__ __launch_bounds__(512, 4) void fused_kernel(
    const float* __restrict__ loc, const float* __restrict__ conf,
    const float* __restrict__ dbox, const float* __restrict__ targets,
    unsigned long long* __restrict__ keys,   // [Bn*On]
    unsigned int* __restrict__ adone,        // [Bn*2]
    unsigned int* __restrict__ nppost,       // [Bn*2]
    unsigned int* __restrict__ hpost,        // [Bn*4*2*256]
    unsigned int* __restrict__ fin,          // [Bn*4]
    unsigned int* __restrict__ res,          // [Bn*4]
    float* __restrict__ out) {
  const int h = blockIdx.x & 1;
  const int b = blockIdx.x >> 1;
  const int tid = threadIdx.x;
  const int wv = tid >> 6, lane = tid & 63;
  const int halfBase = h ? H0CNT : 0;
  const int halfCnt  = h ? H1CNT : H0CNT;
  const int nChunks  = h ? 69 : 68;

  __shared__ float s_stage[8][1344];      // 43008 B; reused as hist in D
  __shared__ float s_ce[H1CNT];           // ce0, local index
  __shared__ unsigned char s_bti[H1CNT];  // bti | pos<<4, local index
  __shared__ float s_tt[80];
  __shared__ float s_ar[On];
  __shared__ float s_mv[On][8];
  __shared__ int   s_mp[On][8];
  __shared__ int   s_bp[On];
  __shared__ float s_redf[2][8];
  __shared__ int   s_redi[8];
  __shared__ int   s_sfx[256];
  __shared__ int   s_wsum[4];
  __shared__ unsigned s_prefix;
  __shared__ int s_kk, s_np;

  unsigned (*hist)[256] = (unsigned (*)[256])s_stage;   // aliases dead staging

  const size_t confBase = (size_t)b * Pn * Cn;

  // issue chunk wv of own half (always full: wv<8 <= 67); hides under A
  {
    const float4* src = (const float4*)(conf + confBase + (size_t)(halfBase + wv * 64) * Cn);
    float4* dst = (float4*)s_stage[wv];
    #pragma unroll
    for (int q = 0; q < 6; q++)
      if (lane + 64 * q < 336) cp16_lds(src + lane + 64 * q, dst + 64 * q);
  }

  if (tid < 80) s_tt[tid] = targets[b * 80 + tid];
  __syncthreads();
  if (tid < On)
    s_ar[tid] = (s_tt[tid*5+2] - s_tt[tid*5+0]) * (s_tt[tid*5+3] - s_tt[tid*5+1]);
  __syncthreads();

  // ---- Phase A: IoU matching over own half ----
  {
    float bestv[On]; int bestp[On];
    #pragma unroll
    for (int j = 0; j < On; j++) { bestv[j] = -1.0f; bestp[j] = 0x7fffffff; }

    for (int lp = tid; lp < halfCnt; lp += 512) {
      const int p = halfBase + lp;
      float4 d = ((const float4*)dbox)[p];
      float px1 = d.x - d.z * 0.5f, py1 = d.y - d.w * 0.5f;
      float px2 = d.x + d.z * 0.5f, py2 = d.y + d.w * 0.5f;
      float ap = d.z * d.w;
      float mv = -1.0f; int mj = 0;
      #pragma unroll
      for (int j = 0; j < On; j++) {
        float lx = fmaxf(s_tt[j*5+0], px1);
        float ly = fmaxf(s_tt[j*5+1], py1);
        float rx = fminf(s_tt[j*5+2], px2);
        float ry = fminf(s_tt[j*5+3], py2);
        float w = fmaxf(rx - lx, 0.0f), hh = fmaxf(ry - ly, 0.0f);
        float inter = w * hh;
        float ov = inter / (s_ar[j] + ap - inter);
        if (ov > bestv[j]) { bestv[j] = ov; bestp[j] = p; }  // smallest p kept
        if (ov > mv) { mv = ov; mj = j; }                    // first max over j
      }
      s_bti[lp] = (unsigned char)(mj | ((mv >= 0.5f) ? 16 : 0));
    }
    #pragma unroll
    for (int j = 0; j < On; j++) {
      float v = bestv[j]; int p = bestp[j];
      #pragma unroll
      for (int off = 32; off; off >>= 1) {
        float v2 = __shfl_down(v, off);
        int p2 = __shfl_down(p, off);
        argmax_combine(v, p, v2, p2);
      }
      if (lane == 0) { s_mv[j][wv] = v; s_mp[j][wv] = p; }
    }
  }
  __syncthreads();
  if (tid < On) {   // combine 8 waves, post key (ov>=0 always; tie -> min p)
    float v = s_mv[tid][0]; int p = s_mp[tid][0];
    #pragma unroll
    for (int w = 1; w < 8; w++) argmax_combine(v, p, s_mv[tid][w], s_mp[tid][w]);
    unsigned long long key =
        (((unsigned long long)(__float_as_uint(v) | 0xC0000000u)) << 32)
        | (unsigned long long)(0xFFFFFFFFu - (unsigned)p);
    atomicMax(&keys[b * On + tid], key);     // beats 0xAA poison
  }
  __threadfence();
  __syncthreads();
  if (tid == 0) atomicExch(&adone[b * 2 + h], MAGIC);

  // ---- Phase B: stream own-half conf, chunks ci = wv + 8*i ----
  for (int ci = wv; ci < nChunks; ci += 8) {
    asm volatile("s_waitcnt vmcnt(0)" ::: "memory");
    const int rows = (h && ci == 68) ? 28 : 64;
    if (lane < rows) {
      const int lp = ci * 64 + lane;
      const float* x = s_stage[wv] + lane * Cn;   // stride-21: 2-way, free
      float m = x[0];
      #pragma unroll
      for (int q = 1; q < Cn; q++) m = fmaxf(m, x[q]);
      float s = 0.0f;
      #pragma unroll
      for (int q = 0; q < Cn; q++) s += expf(x[q] - m);
      s_ce[lp] = m + logf(s) - x[0];              // >= 0 always
    }
    asm volatile("s_waitcnt lgkmcnt(0)" ::: "memory");
    const int cn = ci + 8;
    if (cn < nChunks) {
      const int n4 = (h && cn == 68) ? 147 : 336;
      const float4* src =
          (const float4*)(conf + confBase + (size_t)(halfBase + cn * 64) * Cn);
      float4* dst = (float4*)s_stage[wv];
      #pragma unroll
      for (int q = 0; q < 6; q++)
        if (lane + 64 * q < n4) cp16_lds(src + lane + 64 * q, dst + 64 * q);
    }
  }
  __syncthreads();

  // ---- keys sync + forced overwrites (ascending j: last wins) ----
  if (tid == 0) {
    while (atomicAdd(&adone[b * 2 + (1 - h)], 0u) != MAGIC)
      __builtin_amdgcn_s_sleep(2);
  }
  __syncthreads();
  if (tid < On) {
    unsigned long long k64 = atomicAdd(&keys[b * On + tid], 0ull);
    s_bp[tid] = (int)(0xFFFFFFFFu - (unsigned)(k64 & 0xFFFFFFFFull));
  }
  __syncthreads();
  if (tid == 0) {
    #pragma unroll
    for (int j = 0; j < On; j++) {
      int p = s_bp[j];
      if (p >= halfBase && p < halfBase + halfCnt)
        s_bti[p - halfBase] = (unsigned char)(j | 16);
    }
  }
  __syncthreads();

  // ---- Phase C: ce_neg regs + np/loc/cep partials (own half) ----
  float ce_r[9];
  float my_loc = 0.0f, my_cep = 0.0f; int my_np = 0;
  #pragma unroll
  for (int s9 = 0; s9 < 9; s9++) {
    ce_r[s9] = 0.0f;
    const int lp = tid + 512 * s9;
    if (lp < halfCnt) {
      int pk = s_bti[lp];
      float c0 = s_ce[lp];
      int pos = pk >> 4, bt = pk & 15;
      ce_r[s9] = pos ? 0.0f : c0;
      if (pos) {
        my_np++;
        const int p = halfBase + lp;
        const float* t = &s_tt[bt * 5];
        int c = (int)t[4] + 1;
        const float* row = conf + confBase + (size_t)p * Cn;
        my_cep += c0 + row[0] - row[c];            // lse - x[c]
        float4 d = ((const float4*)dbox)[p];
        float mx1 = t[0], my1 = t[1], mx2 = t[2], my2 = t[3];
        float g0 = ((mx1 + mx2) * 0.5f - d.x) / (0.1f * d.z);
        float g1 = ((my1 + my2) * 0.5f - d.y) / (0.1f * d.w);
        float g2 = logf((mx2 - mx1) / d.z) / 0.2f;
        float g3 = logf((my2 - my1) / d.w) / 0.2f;
        float4 ld = ((const float4*)loc)[(size_t)b * Pn + p];
        float g[4] = {g0, g1, g2, g3};
        float l[4] = {ld.x, ld.y, ld.z, ld.w};
        #pragma unroll
        for (int q = 0; q < 4; q++) {
          float ad = fabsf(l[q] - g[q]);
          my_loc += (ad < 1.0f) ? 0.5f * ad * ad : ad - 0.5f;
        }
      }
    }
  }
  {
    int np = my_np;
    #pragma unroll
    for (int off = 32; off; off >>= 1) np += __shfl_down(np, off);
    if (lane == 0) s_redi[wv] = np;
  }
  __syncthreads();
  if (tid == 0) {
    int np = 0;
    #pragma unroll
    for (int w = 0; w < 8; w++) np += s_redi[w];
    atomicExch(&nppost[b * 2 + h], 0x5A5A0000u | (unsigned)np);
    unsigned v;
    while (((v = atomicAdd(&nppost[b * 2 + (1 - h)], 0u)) >> 16) != 0x5A5Au)
      __builtin_amdgcn_s_sleep(2);
    s_np = np + (int)(v & 0xFFFFu);
  }
  __syncthreads();

  // ---- Phase D: exact radix select, PAIR LOCKSTEP histogram exchange ----
  const int k = min(s_np * 3, Pn);
  int kk = max(k, 1);
  unsigned prefix = 0, maskb = 0;
  #pragma unroll
  for (int s = 0; s < 4; s++) {
    const int shift = 24 - 8 * s;
    #pragma unroll
    for (int j = 0; j < 4; j++) hist[wv][lane * 4 + j] = 0;
    __syncthreads();
    #pragma unroll
    for (int s9 = 0; s9 < 9; s9++) {
      const int lp = tid + 512 * s9;
      if (lp < halfCnt) {
        unsigned u = __float_as_uint(ce_r[s9]);
        if ((u & maskb) == prefix) atomicAdd(&hist[wv][(u >> shift) & 255u], 1u);
      }
    }
    __syncthreads();
    int v = 0;
    if (tid < 256) {
      unsigned hown = 0;
      #pragma unroll
      for (int w = 0; w < 8; w++) hown += hist[w][tid];
      // exchange with partner (distinct region per (image,pass,half): no race)
      const unsigned tag = (0x5B00u + s) << 16;
      atomicExch(&hpost[(((size_t)b * 4 + s) * 2 + h) * 256 + tid], tag | hown);
      unsigned pv;
      unsigned int* pslot = &hpost[(((size_t)b * 4 + s) * 2 + (1 - h)) * 256 + tid];
      while (((pv = atomicAdd(pslot, 0u)) & 0xFFFF0000u) != tag)
        __builtin_amdgcn_s_sleep(2);
      v = (int)(hown + (pv & 0xFFFFu));
      #pragma unroll
      for (int off = 1; off < 64; off <<= 1) {      // in-wave suffix scan
        int u2 = __shfl_down(v, off);
        if (lane + off < 64) v += u2;
      }
      if (lane == 0) s_wsum[tid >> 6] = v;
    }
    __syncthreads();
    if (tid < 256) {
      int S = v;
      #pragma unroll
      for (int w = 0; w < 4; w++) if (w > (tid >> 6)) S += s_wsum[w];
      s_sfx[tid] = S;
    }
    __syncthreads();
    if (tid < 256) {
      int S = s_sfx[tid];
      int Snext = (tid == 255) ? 0 : s_sfx[tid + 1];
      if (S >= kk && Snext < kk) {                  // exactly one bin
        s_prefix = prefix | ((unsigned)tid << shift);
        s_kk = kk - Snext;
      }
    }
    __syncthreads();
    prefix = s_prefix; kk = s_kk;
    maskb |= 255u << shift;
    __syncthreads();
  }
  const float T = __uint_as_float(prefix);

  float sum_gt = 0.0f; int cnt_gt = 0;
  #pragma unroll
  for (int s9 = 0; s9 < 9; s9++) {
    const int lp = tid + 512 * s9;
    if (lp < halfCnt) {
      float x = ce_r[s9];
      if (x > T) { sum_gt += x; cnt_gt++; }
    }
  }
  #pragma unroll
  for (int off = 32; off; off >>= 1) {
    sum_gt += __shfl_down(sum_gt, off);
    cnt_gt += __shfl_down(cnt_gt, off);
    my_loc += __shfl_down(my_loc, off);
    my_cep += __shfl_down(my_cep, off);
  }
  if (lane == 0) {
    s_redf[0][wv] = my_loc;
    s_redf[1][wv] = sum_gt + my_cep;
    s_redi[wv] = cnt_gt;
  }
  __syncthreads();

  // ---- Phase E ----
  if (tid == 0) {
    float loc_o = 0.0f, cg_o = 0.0f; int cnt_o = 0;
    #pragma unroll
    for (int w = 0; w < 8; w++) {
      loc_o += s_redf[0][w]; cg_o += s_redf[1][w]; cnt_o += s_redi[w];
    }
    if (h == 1) {
      atomicExch(&fin[b * 4 + 0], __float_as_uint(loc_o));
      atomicExch(&fin[b * 4 + 1], __float_as_uint(cg_o));
      atomicExch(&fin[b * 4 + 2], (unsigned)cnt_o);
      __threadfence();
      atomicExch(&fin[b * 4 + 3], MAGIC);
    } else {
      while (atomicAdd(&fin[b * 4 + 3], 0u) != MAGIC) __builtin_amdgcn_s_sleep(2);
      float ll = loc_o + __uint_as_float(atomicAdd(&fin[b * 4 + 0], 0u));
      float lc = cg_o + __uint_as_float(atomicAdd(&fin[b * 4 + 1], 0u));
      int cg = cnt_o + (int)atomicAdd(&fin[b * 4 + 2], 0u);
      if (k > 0) lc += (float)(k - cg) * T;
      atomicExch(&res[b * 4 + 0], __float_as_uint(ll));
      atomicExch(&res[b * 4 + 1], __float_as_uint(lc));
      atomicExch(&res[b * 4 + 2], (unsigned)s_np);
      __threadfence();
      atomicExch(&res[b * 4 + 3], MAGIC);
    }
  }

  if (blockIdx.x == 0 && tid < 64) {   // gather 128 image results
    float ll = 0.0f, lc = 0.0f; int np = 0;
    #pragma unroll
    for (int g = 0; g < 2; g++) {
      const int i = tid + 64 * g;
      while (atomicAdd(&res[i * 4 + 3], 0u) != MAGIC) __builtin_amdgcn_s_sleep(8);
      ll += __uint_as_float(atomicAdd(&res[i * 4 + 0], 0u));
      lc += __uint_as_float(atomicAdd(&res[i * 4 + 1], 0u));
      np += (int)atomicAdd(&res[i * 4 + 2], 0u);
    }
    #pragma unroll
    for (int off = 32; off; off >>= 1) {
      ll += __shfl_down(ll, off);
      lc += __shfl_down(lc, off);
      np += __shfl_down(np, off);
    }
    if (tid == 0) {
      float fN = (float)np;
      out[0] = ll / fN;
      out[1] = lc / fN;
    }
  }
}

extern "C" void kernel_launch(void* const* d_in, const int* in_sizes, int n_in,
                              void* d_out, int out_size, void* d_ws, size_t ws_size,
                              hipStream_t stream) {
  const float* loc_data  = (const float*)d_in[0];
  const float* conf_data = (const float*)d_in[1];
  const float* dbox      = (const float*)d_in[2];
  const float* targets   = (const float*)d_in[3];
  float* out = (float*)d_out;

  char* ws = (char*)d_ws;   // all slots poison-tagged; no init needed
  unsigned long long* keys = (unsigned long long*)ws;                 // 16 KB
  unsigned int* adone  = (unsigned int*)(ws + 16384);                 // 1 KB
  unsigned int* nppost = (unsigned int*)(ws + 16384 + 1024);          // 1 KB
  unsigned int* fin    = (unsigned int*)(ws + 16384 + 2048);          // 2 KB
  unsigned int* res    = (unsigned int*)(ws + 16384 + 4096);          // 2 KB
  unsigned int* hpost  = (unsigned int*)(ws + 16384 + 8192);          // 1 MB

  fused_kernel<<<2 * Bn, 512, 0, stream>>>(loc_data, conf_data, dbox, targets,
                                           keys, adone, nppost, hpost, fin, res, out);
}